// Round 1
// baseline (132.106 us; speedup 1.0000x reference)
//
#include <hip/hip_runtime.h>
#include <stdint.h>

#pragma clang fp contract(off)

#define NA 10
#define LL 4096
#define NB 4
#define NSEL (LL * NA)        // 40960 proposals per image
#define PRE2 2048             // NMS candidate window (prefix-stable: 300 kept << 2048)
#define POST_NMS 300
#define CAND 4096             // candidate buffer (threshold overshoot bound)
#define NHB 65536             // 16-bit-prefix histogram buckets
#define TWORDS 33792          // col-major mask words per image: 64 * sum_{w=0..31}(w+1)

__constant__ float c_WS[NA] = {16.f, 32.f, 40.f, 48.f, 64.f, 72.f, 80.f, 96.f, 112.f, 128.f};

// async global->LDS DMA: per-lane 16B from g (per-lane addr), lands at uniform dst + lane*16
__device__ inline void gload_lds16(const void* g, void* l) {
    __builtin_amdgcn_global_load_lds(
        (const __attribute__((address_space(1))) unsigned*)g,
        (__attribute__((address_space(3))) unsigned*)l, 16, 0, 0);
}

// ---------------- Kernel 1: decode + sort keys + chip-wide 16-bit histogram ----------------
__global__ __launch_bounds__(256) void k_prep(const float* __restrict__ scores,
                                              const float* __restrict__ deltas,
                                              unsigned long long* __restrict__ packed,
                                              float2* __restrict__ prop,
                                              unsigned* __restrict__ ghist) {
    int g = blockIdx.x * 256 + threadIdx.x;
    if (g >= NB * NSEL) return;
    int b = g / NSEL;
    int r = g - b * NSEL;          // r = a*4096 + l  (coalesced input reads)
    int a = r >> 12;
    int l = r & 4095;

    float w   = c_WS[a];
    float ctr = (float)(8 * l + 4);            // exact: anchor center
    float sc  = scores[((b * 20 + 10 + a) << 12) + l];
    float d0  = deltas[((b * 20 + 2 * a) << 12) + l];
    float d1  = deltas[((b * 20 + 2 * a + 1) << 12) + l];

    float pc = d0 * w + ctr;                   // contract(off): mul then add, matches numpy
    float pl = expf(d1) * w;
    float x1 = pc - 0.5f * pl;
    float x2 = pc + 0.5f * pl;
    x1 = fminf(fmaxf(x1, 0.0f), 32767.0f);
    x2 = fminf(fmaxf(x2, 0.0f), 32767.0f);
    float ls = x2 - x1 + 1.0f;
    if (ls < 8.0f) sc = 0.0f;

    unsigned u = __float_as_uint(sc);
    unsigned key = (u & 0x80000000u) ? ~u : (u | 0x80000000u);   // ascending uint == ascending float
    int i = l * NA + a;                                          // reference's flat index
    packed[b * NSEL + r] = ((unsigned long long)key << 32) | (unsigned)(0xFFFFFFFFu - (unsigned)i);
    prop[b * NSEL + r] = make_float2(x1, x2);   // r-indexed: coalesced write (gather converts)
    atomicAdd(&ghist[b * NHB + (key >> 16)], 1u);   // ~1-2 hits/address: uncontended atomics
}

// ---------------- Kernel 2a: threshold find (hierarchical shfl scans over ghist) ----------------
// Verbatim phases A-C of the old k_select; emits kmin[b] and zeroes gcnt[b].
__global__ __launch_bounds__(1024) void k_thresh(const unsigned* __restrict__ ghist,
                                                 unsigned* __restrict__ kminArr,
                                                 int* __restrict__ gcnt) {
    __shared__ unsigned coarse[64];
    __shared__ unsigned wsum[16];
    __shared__ unsigned sAfter;
    __shared__ int sC;

    const int tid = threadIdx.x;
    const int lane = tid & 63;
    const int wv = tid >> 6;
    const int b = blockIdx.x;
    const unsigned* gh = ghist + b * NHB;

    if (tid == 0) gcnt[b] = 0;

    // --- Phase A: coarse sums of 64 chunks (1024 buckets each), coalesced reads ---
    #pragma unroll
    for (int cc = 0; cc < 4; ++cc) {
        int c = (wv << 2) + cc;
        const unsigned* gc = gh + (c << 10);
        unsigned s = 0;
        #pragma unroll
        for (int k = 0; k < 16; ++k) s += gc[(k << 6) + lane];
        #pragma unroll
        for (int d = 1; d < 64; d <<= 1) s += (unsigned)__shfl_xor((int)s, d, 64);
        if (lane == 0) coarse[c] = s;
    }
    __syncthreads();

    // --- Phase B: wave 0 suffix-scans 64 chunk sums, finds crossing chunk ---
    if (wv == 0) {
        unsigned v = coarse[lane];
        unsigned inc = v;
        #pragma unroll
        for (int d = 1; d < 64; d <<= 1) {
            unsigned u = (unsigned)__shfl_down((int)inc, d, 64);
            if (lane + d < 64) inc += u;
        }
        if (inc >= (unsigned)PRE2 && (inc - v) < (unsigned)PRE2) { sC = lane; sAfter = inc - v; }
    }
    __syncthreads();

    // --- Phase C: scan crossing chunk's 1024 buckets (coalesced, shfl-hierarchical) ---
    {
        const int C = sC;
        const unsigned after = sAfter;
        unsigned v = gh[(C << 10) + tid];
        unsigned inc = v;
        #pragma unroll
        for (int d = 1; d < 64; d <<= 1) {
            unsigned u = (unsigned)__shfl_down((int)inc, d, 64);
            if (lane + d < 64) inc += u;
        }
        if (lane == 0) wsum[wv] = inc;
        __syncthreads();
        if (tid < 16) {
            unsigned t = wsum[tid];
            unsigned winc = t;
            #pragma unroll
            for (int d = 1; d < 16; d <<= 1) {
                unsigned u = (unsigned)__shfl_down((int)winc, d, 64);
                if (tid + d < 16) winc += u;
            }
            wsum[tid] = winc - t;            // sum of waves strictly after tid
        }
        __syncthreads();
        unsigned glob = inc + wsum[wv] + after;      // suffix including own bucket
        if (glob >= (unsigned)PRE2 && (glob - v) < (unsigned)PRE2)
            kminArr[b] = ((unsigned)((C << 10) + tid)) << 16;
    }
}

// ---------------- Kernel 2b: wide unordered compaction (block-aggregated atomics) ----------------
// Order within cand is irrelevant: k_rank reconstructs the exact descending order.
// grid (NSEL/1024, NB) x 1024 -> 160 blocks (vs 4 before)
__global__ __launch_bounds__(1024) void k_compact(const unsigned long long* __restrict__ packed,
                                                  const unsigned* __restrict__ kminArr,
                                                  int* __restrict__ gcnt,
                                                  unsigned long long* __restrict__ cand) {
    __shared__ int woff[16];
    __shared__ int sbase;
    const int b = blockIdx.y;
    const int tid = threadIdx.x;
    const int lane = tid & 63;
    const int wv = tid >> 6;

    const unsigned km = kminArr[b];
    const unsigned long long p = packed[b * NSEL + (blockIdx.x << 10) + tid];
    const bool pred = ((unsigned)(p >> 32) >= km);
    const unsigned long long m = __ballot(pred);
    if (lane == 0) woff[wv] = (int)__popcll(m);
    __syncthreads();
    if (tid < 16) {
        int v = woff[tid];
        int inc = v;
        #pragma unroll
        for (int d = 1; d < 16; d <<= 1) {
            int u = __shfl_up(inc, d, 64);
            if (tid >= d) inc += u;
        }
        woff[tid] = inc - v;                 // exclusive prefix over waves
        if (tid == 15) sbase = atomicAdd(&gcnt[b], inc);   // one global atomic per block
    }
    __syncthreads();
    if (pred) {
        int pos = sbase + woff[wv] + (int)__popcll(m & ((1ULL << lane) - 1ULL));
        if (pos < CAND) cand[b * CAND + pos] = p;
    }
}

// ---------------- Kernel 2c: O(n^2) rank-scatter (replaces the bitonic sort) ----------------
// rank_i = #{j : key_j > key_i}. Keys unique (low word = 0xFFFFFFFF - i) so this is the
// exact descending-sort position with the same tie-breaking as the old 64-bit bitonic sort.
// Inner loop address is wave-uniform -> compiler emits batched s_load; ~2 VALU/key.
// grid (CAND/256, NB) x 256 -> ~36 active blocks spread over CUs (vs 4 before)
__global__ __launch_bounds__(256) void k_rank(const unsigned long long* __restrict__ cand,
                                              const int* __restrict__ gcnt,
                                              const float2* __restrict__ prop,
                                              float2* __restrict__ srt) {
    const int b = blockIdx.y;
    const int n0 = gcnt[b];
    const int n = n0 < CAND ? n0 : CAND;
    if ((int)(blockIdx.x * 256) >= n) return;

    const unsigned long long* cb = cand + b * CAND;
    const int i = blockIdx.x * 256 + (int)threadIdx.x;
    unsigned long long k = 0ULL;
    if (i < n) k = cb[i];

    int r = 0;
    int j = 0;
    for (; j + 16 <= n; j += 16) {
        #pragma unroll
        for (int u = 0; u < 16; ++u) r += (cb[j + u] > k) ? 1 : 0;
    }
    for (; j < n; ++j) r += (cb[j] > k) ? 1 : 0;

    if (i < n && r < PRE2) {
        unsigned idx_ = 0xFFFFFFFFu - (unsigned)k;
        unsigned a_ = idx_ % 10u, l_ = idx_ / 10u;
        srt[b * PRE2 + r] = prop[b * NSEL + (a_ << 12) + l_];
    }
}

// ---------------- Kernel 3: COLUMN-major suppression mask over top-2048 ----------------
// For candidate j (window wj) and suppressor word wi <= wj: bit t = "cand wi*64+t
// suppresses j" (i<j && IoU>0.7). IoU math commutative-identical to row-major version.
// grid: (8 wi-groups, 32 wj, NB); block 256 = 4 wi-words x 64 j-lanes
__global__ __launch_bounds__(256) void k_mask(const float2* __restrict__ srt,
                                              unsigned long long* __restrict__ maskT) {
    const int g  = blockIdx.x;          // wi in [4g, 4g+3]
    const int wj = blockIdx.y;
    const int b  = blockIdx.z;
    if (g * 4 > wj) return;             // whole group above diagonal

    __shared__ float2 lj[256];
    const int tid = threadIdx.x;
    lj[tid] = srt[b * PRE2 + (g << 8) + tid];    // suppressor candidates (4 words)
    __syncthreads();

    const int wi = (g << 2) + (tid >> 6);
    if (wi > wj) return;
    const int j = (wj << 6) + (tid & 63);

    float2 pj = srt[b * PRE2 + j];
    float ljn = pj.y - pj.x + 1.0f;
    unsigned long long bits = 0ULL;
    const int lbase = (tid >> 6) * 64;
    const int ibase = wi << 6;
    #pragma unroll 4
    for (int t = 0; t < 64; ++t) {
        float2 pv = lj[lbase + t];
        float inter = fminf(pj.y, pv.y) - fmaxf(pj.x, pv.x) + 1.0f;
        bool sup = false;
        if (inter > 0.0f) {
            float uni = ljn + (pv.y - pv.x + 1.0f) - inter;
            sup = (inter / uni) > 0.7f;          // IEEE div, same rounding as reference
        }
        if ((ibase + t < j) && sup) bits |= (1ULL << t);
    }
    maskT[(size_t)b * TWORDS + (size_t)((wj * (wj + 1) / 2) + wi) * 64 + (tid & 63)] = bits;
}

// ---------------- Kernel 4: single-wave reduce, column-prefetch greedy (NO apply step) ----------------
// Column-major mask: window w needs SUP_j = OR_{wi<w}(K[wi] & colT[w][wi][j]) — colT is
// STATIC, prefetched one window ahead via global_load_lds DMA (double-buffered LDS);
// K is a 32-word LDS bitset updated by one write/window. Serial chain pure VALU/LDS.
__global__ __launch_bounds__(64, 1) void k_reduce(const unsigned long long* __restrict__ maskT,
                                                  const float2* __restrict__ srt,
                                                  float* __restrict__ out) {
    const int b = blockIdx.x;
    const int lane = threadIdx.x;
    __shared__ unsigned long long colbuf[2][2048];   // 2 x 16 KB double buffer
    __shared__ unsigned long long Kl[32];            // kept bitset per window
    __shared__ int sKl[POST_NMS];

    const unsigned long long* mTb = maskT + (size_t)b * TWORDS;

    // stage window wv's column block ((wv+1) words x 64 lanes) into colbuf[wv&1]
    auto stage = [&](int wv) {
        const int nIns = (wv + 2) >> 1;              // ceil((wv+1)*512B / 1024B)
        const char* src = (const char*)(mTb + (size_t)(wv * (wv + 1) / 2) * 64) + lane * 16;
        char* dst = (char*)(&colbuf[wv & 1][0]);
        for (int k = 0; k < nIns; ++k)
            gload_lds16(src + k * 1024, dst + k * 1024);
    };

    stage(0);                                        // prologue

    int kept = 0;
    bool done = false;

    for (int w = 0; w < 32 && !done; ++w) {
        asm volatile("s_waitcnt vmcnt(0)" ::: "memory");
        __builtin_amdgcn_sched_barrier(0);
        if (w < 31) stage(w + 1);                    // prefetch next (other buffer)

        const unsigned long long* cw = &colbuf[w & 1][0];
        unsigned long long SUP = 0ULL;
        for (int wi = 0; wi < w; ++wi)
            SUP |= Kl[wi] & cw[(wi << 6) + lane];    // broadcast K read + per-lane col read
        unsigned long long x = cw[(w << 6) + lane];  // within-window suppressor column

        unsigned long long avail = ~__ballot(SUP != 0ULL);
        unsigned long long keptw = 0ULL;
        while (avail) {
            int j = __ffsll((long long)avail) - 1;   // wave-uniform
            if (lane == 0) sKl[kept] = (w << 6) + j;
            kept++; keptw |= (1ULL << j);
            if (kept >= POST_NMS) { done = true; break; }
            unsigned long long supb = __ballot(((x >> j) & 1ULL) != 0ULL);
            avail &= ~supb;
            avail &= ~(1ULL << j);
        }
        if (lane == 0) Kl[w] = keptw;
    }

    __syncthreads();
    for (int t = lane; t < POST_NMS; t += 64) {
        float x1 = 0.0f, x2 = 0.0f;
        if (t < kept) {
            float2 pv = srt[b * PRE2 + sKl[t]];
            x1 = pv.x; x2 = pv.y;
        }
        float* o = out + (size_t)(b * POST_NMS + t) * 3;
        o[0] = (float)b; o[1] = x1; o[2] = x2;
    }
}

extern "C" void kernel_launch(void* const* d_in, const int* in_sizes, int n_in,
                              void* d_out, int out_size, void* d_ws, size_t ws_size,
                              hipStream_t stream) {
    const float* scores = (const float*)d_in[0];
    const float* deltas = (const float*)d_in[1];
    float* out = (float*)d_out;

    char* ws = (char*)d_ws;
    unsigned long long* packed = (unsigned long long*)ws;                   // 1,310,720 B
    float2* prop = (float2*)(ws + 1310720);                                 // 1,310,720 B
    float2* srt  = (float2*)(ws + 2621440);                                 //    65,536 B
    unsigned long long* maskT = (unsigned long long*)(ws + 2686976);        // 1,081,344 B
    unsigned* ghist = (unsigned*)(ws + 3768320);                            // 1,048,576 B

    // Aliases (no new workspace):
    //  - cand lives in ghist's region: ghist is dead after k_thresh, re-zeroed next iter.
    //  - kmin/gcnt live in maskT's head: dead by the time k_mask rewrites every maskT
    //    word that k_reduce later reads.
    unsigned long long* cand = (unsigned long long*)(ws + 3768320);
    unsigned* kminArr = (unsigned*)(ws + 2686976);
    int* gcnt = (int*)(ws + 2686976 + 64);

    hipMemsetAsync(ghist, 0, (size_t)NB * NHB * sizeof(unsigned), stream);
    k_prep<<<(NB * NSEL + 255) / 256, 256, 0, stream>>>(scores, deltas, packed, prop, ghist);
    k_thresh<<<NB, 1024, 0, stream>>>(ghist, kminArr, gcnt);
    k_compact<<<dim3(NSEL / 1024, NB), 1024, 0, stream>>>(packed, kminArr, gcnt, cand);
    k_rank<<<dim3(CAND / 256, NB), 256, 0, stream>>>(cand, gcnt, prop, srt);
    k_mask<<<dim3(8, 32, NB), 256, 0, stream>>>(srt, maskT);
    k_reduce<<<NB, 64, 0, stream>>>(maskT, srt, out);
}

// Round 2
// 101.709 us; speedup vs baseline: 1.2989x; 1.2989x over previous
//
#include <hip/hip_runtime.h>
#include <stdint.h>

#pragma clang fp contract(off)

#define NA 10
#define LL 4096
#define NB 4
#define NSEL (LL * NA)        // 40960 proposals per image
#define PRE2 2048             // NMS candidate window (prefix-stable: 300 kept << 2048)
#define POST_NMS 300
#define CAND 4096             // candidate buffer (threshold overshoot bound)
#define NHB 65536             // 16-bit-prefix histogram buckets
#define TWORDS 33792          // col-major mask words per image: 64 * sum_{w=0..31}(w+1)

__constant__ float c_WS[NA] = {16.f, 32.f, 40.f, 48.f, 64.f, 72.f, 80.f, 96.f, 112.f, 128.f};

// async global->LDS DMA: per-lane 16B from g (per-lane addr), lands at uniform dst + lane*16
__device__ inline void gload_lds16(const void* g, void* l) {
    __builtin_amdgcn_global_load_lds(
        (const __attribute__((address_space(1))) unsigned*)g,
        (__attribute__((address_space(3))) unsigned*)l, 16, 0, 0);
}

// ---------------- Kernel 1: decode + sort keys + chip-wide 16-bit histogram ----------------
__global__ __launch_bounds__(256) void k_prep(const float* __restrict__ scores,
                                              const float* __restrict__ deltas,
                                              unsigned long long* __restrict__ packed,
                                              float2* __restrict__ prop,
                                              unsigned* __restrict__ ghist) {
    int g = blockIdx.x * 256 + threadIdx.x;
    if (g >= NB * NSEL) return;
    int b = g / NSEL;
    int r = g - b * NSEL;          // r = a*4096 + l  (coalesced input reads)
    int a = r >> 12;
    int l = r & 4095;

    float w   = c_WS[a];
    float ctr = (float)(8 * l + 4);            // exact: anchor center
    float sc  = scores[((b * 20 + 10 + a) << 12) + l];
    float d0  = deltas[((b * 20 + 2 * a) << 12) + l];
    float d1  = deltas[((b * 20 + 2 * a + 1) << 12) + l];

    float pc = d0 * w + ctr;                   // contract(off): mul then add, matches numpy
    float pl = expf(d1) * w;
    float x1 = pc - 0.5f * pl;
    float x2 = pc + 0.5f * pl;
    x1 = fminf(fmaxf(x1, 0.0f), 32767.0f);
    x2 = fminf(fmaxf(x2, 0.0f), 32767.0f);
    float ls = x2 - x1 + 1.0f;
    if (ls < 8.0f) sc = 0.0f;

    unsigned u = __float_as_uint(sc);
    unsigned key = (u & 0x80000000u) ? ~u : (u | 0x80000000u);   // ascending uint == ascending float
    int i = l * NA + a;                                          // reference's flat index
    packed[b * NSEL + r] = ((unsigned long long)key << 32) | (unsigned)(0xFFFFFFFFu - (unsigned)i);
    prop[b * NSEL + r] = make_float2(x1, x2);   // r-indexed: coalesced write (gather converts)
    atomicAdd(&ghist[b * NHB + (key >> 16)], 1u);   // ~1-2 hits/address: uncontended atomics
}

// ---------------- Kernel 2a: threshold find (hierarchical shfl scans over ghist) ----------------
__global__ __launch_bounds__(1024) void k_thresh(const unsigned* __restrict__ ghist,
                                                 unsigned* __restrict__ kminArr,
                                                 int* __restrict__ gcnt) {
    __shared__ unsigned coarse[64];
    __shared__ unsigned wsum[16];
    __shared__ unsigned sAfter;
    __shared__ int sC;

    const int tid = threadIdx.x;
    const int lane = tid & 63;
    const int wv = tid >> 6;
    const int b = blockIdx.x;
    const unsigned* gh = ghist + b * NHB;

    if (tid == 0) gcnt[b] = 0;

    // --- Phase A: coarse sums of 64 chunks (1024 buckets each), coalesced reads ---
    #pragma unroll
    for (int cc = 0; cc < 4; ++cc) {
        int c = (wv << 2) + cc;
        const unsigned* gc = gh + (c << 10);
        unsigned s = 0;
        #pragma unroll
        for (int k = 0; k < 16; ++k) s += gc[(k << 6) + lane];
        #pragma unroll
        for (int d = 1; d < 64; d <<= 1) s += (unsigned)__shfl_xor((int)s, d, 64);
        if (lane == 0) coarse[c] = s;
    }
    __syncthreads();

    // --- Phase B: wave 0 suffix-scans 64 chunk sums, finds crossing chunk ---
    if (wv == 0) {
        unsigned v = coarse[lane];
        unsigned inc = v;
        #pragma unroll
        for (int d = 1; d < 64; d <<= 1) {
            unsigned u = (unsigned)__shfl_down((int)inc, d, 64);
            if (lane + d < 64) inc += u;
        }
        if (inc >= (unsigned)PRE2 && (inc - v) < (unsigned)PRE2) { sC = lane; sAfter = inc - v; }
    }
    __syncthreads();

    // --- Phase C: scan crossing chunk's 1024 buckets (coalesced, shfl-hierarchical) ---
    {
        const int C = sC;
        const unsigned after = sAfter;
        unsigned v = gh[(C << 10) + tid];
        unsigned inc = v;
        #pragma unroll
        for (int d = 1; d < 64; d <<= 1) {
            unsigned u = (unsigned)__shfl_down((int)inc, d, 64);
            if (lane + d < 64) inc += u;
        }
        if (lane == 0) wsum[wv] = inc;
        __syncthreads();
        if (tid < 16) {
            unsigned t = wsum[tid];
            unsigned winc = t;
            #pragma unroll
            for (int d = 1; d < 16; d <<= 1) {
                unsigned u = (unsigned)__shfl_down((int)winc, d, 64);
                if (tid + d < 16) winc += u;
            }
            wsum[tid] = winc - t;            // sum of waves strictly after tid
        }
        __syncthreads();
        unsigned glob = inc + wsum[wv] + after;      // suffix including own bucket
        if (glob >= (unsigned)PRE2 && (glob - v) < (unsigned)PRE2)
            kminArr[b] = ((unsigned)((C << 10) + tid)) << 16;
    }
}

// ---------------- Kernel 2b: wide unordered compaction (block-aggregated atomics) ----------------
__global__ __launch_bounds__(1024) void k_compact(const unsigned long long* __restrict__ packed,
                                                  const unsigned* __restrict__ kminArr,
                                                  int* __restrict__ gcnt,
                                                  unsigned long long* __restrict__ cand) {
    __shared__ int woff[16];
    __shared__ int sbase;
    const int b = blockIdx.y;
    const int tid = threadIdx.x;
    const int lane = tid & 63;
    const int wv = tid >> 6;

    const unsigned km = kminArr[b];
    const unsigned long long p = packed[b * NSEL + (blockIdx.x << 10) + tid];
    const bool pred = ((unsigned)(p >> 32) >= km);
    const unsigned long long m = __ballot(pred);
    if (lane == 0) woff[wv] = (int)__popcll(m);
    __syncthreads();
    if (tid < 16) {
        int v = woff[tid];
        int inc = v;
        #pragma unroll
        for (int d = 1; d < 16; d <<= 1) {
            int u = __shfl_up(inc, d, 64);
            if (tid >= d) inc += u;
        }
        woff[tid] = inc - v;                 // exclusive prefix over waves
        if (tid == 15) sbase = atomicAdd(&gcnt[b], inc);   // one global atomic per block
    }
    __syncthreads();
    if (pred) {
        int pos = sbase + woff[wv] + (int)__popcll(m & ((1ULL << lane) - 1ULL));
        if (pos < CAND) cand[b * CAND + pos] = p;
    }
}

// ---------------- Kernel 2c: rank-scatter, LDS-staged (replaces serial scalar-load chain) ----------------
// Round-1 post-mortem: the wave-uniform s_load loop was 131 DEPENDENT batches x ~900cy
// (all blocks lockstep -> every batch a cold HBM miss) = 49.5us. Fix: bulk coalesced
// stage of all keys into LDS (one overlapped round trip), then broadcast ds_read_b128
// inner loop. j-split across the 4 waves + R=4 register blocking cuts per-CU LDS
// instruction count 4x. Ranks are exact descending-sort positions (keys unique).
__global__ __launch_bounds__(256) void k_rank(const unsigned long long* __restrict__ cand,
                                              const int* __restrict__ gcnt,
                                              const float2* __restrict__ prop,
                                              float2* __restrict__ srt) {
    __shared__ __align__(16) unsigned long long keys[CAND];   // 32 KB
    __shared__ unsigned part[4][64][4];                        // 4 KB partial ranks

    const int b = blockIdx.y;
    const int n0 = gcnt[b];
    const int n = n0 < CAND ? n0 : CAND;
    const int ib = blockIdx.x * 256;
    if (ib >= n) return;                       // uniform per block: safe before syncs

    const int tid = threadIdx.x;
    const int lane = tid & 63;
    const int wv = tid >> 6;
    const unsigned long long* cb = cand + b * CAND;

    // --- stage: coalesced bulk load, zero-pad to multiple of 8 (0 never outranks a real key) ---
    const int nP = (n + 7) & ~7;
    for (int j = tid; j < nP; j += 256)
        keys[j] = (j < n) ? cb[j] : 0ULL;
    __syncthreads();

    // --- my 4 candidates' keys (i = ib + 4*lane + c) ---
    const int i0 = ib + (lane << 2);
    unsigned long long k0 = keys[i0 + 0] ;     // reads beyond n return pad 0 -> guarded at scatter
    unsigned long long k1 = keys[i0 + 1];
    unsigned long long k2 = keys[i0 + 2];
    unsigned long long k3 = keys[i0 + 3];

    // --- wave wv scans j-slice [wv*q, wv*q+q), q even -> 16B-aligned pair reads ---
    const int q = nP >> 2;
    const ulonglong2* keys2 = (const ulonglong2*)keys;
    const int p0 = (wv * q) >> 1;
    const int pn = q >> 1;
    unsigned r0 = 0, r1 = 0, r2 = 0, r3 = 0;
    #pragma unroll 4
    for (int p = 0; p < pn; ++p) {
        ulonglong2 kj = keys2[p0 + p];         // broadcast (all lanes same addr): conflict-free
        r0 += (kj.x > k0); r0 += (kj.y > k0);
        r1 += (kj.x > k1); r1 += (kj.y > k1);
        r2 += (kj.x > k2); r2 += (kj.y > k2);
        r3 += (kj.x > k3); r3 += (kj.y > k3);
    }
    part[wv][lane][0] = r0; part[wv][lane][1] = r1;
    part[wv][lane][2] = r2; part[wv][lane][3] = r3;
    __syncthreads();

    // --- combine partials, decode, gather box, scatter to rank position ---
    const int ig = ib + tid;
    if (ig < n) {
        const int l_ = tid >> 2, c_ = tid & 3;
        unsigned r = part[0][l_][c_] + part[1][l_][c_] + part[2][l_][c_] + part[3][l_][c_];
        if (r < PRE2) {
            unsigned long long k = keys[ig];
            unsigned idx_ = 0xFFFFFFFFu - (unsigned)k;
            unsigned a_ = idx_ % 10u, l2_ = idx_ / 10u;
            srt[b * PRE2 + r] = prop[b * NSEL + (a_ << 12) + l2_];
        }
    }
}

// ---------------- Kernel 3: COLUMN-major suppression mask over top-2048 ----------------
__global__ __launch_bounds__(256) void k_mask(const float2* __restrict__ srt,
                                              unsigned long long* __restrict__ maskT) {
    const int g  = blockIdx.x;          // wi in [4g, 4g+3]
    const int wj = blockIdx.y;
    const int b  = blockIdx.z;
    if (g * 4 > wj) return;             // whole group above diagonal

    __shared__ float2 lj[256];
    const int tid = threadIdx.x;
    lj[tid] = srt[b * PRE2 + (g << 8) + tid];    // suppressor candidates (4 words)
    __syncthreads();

    const int wi = (g << 2) + (tid >> 6);
    if (wi > wj) return;
    const int j = (wj << 6) + (tid & 63);

    float2 pj = srt[b * PRE2 + j];
    float ljn = pj.y - pj.x + 1.0f;
    unsigned long long bits = 0ULL;
    const int lbase = (tid >> 6) * 64;
    const int ibase = wi << 6;
    #pragma unroll 4
    for (int t = 0; t < 64; ++t) {
        float2 pv = lj[lbase + t];
        float inter = fminf(pj.y, pv.y) - fmaxf(pj.x, pv.x) + 1.0f;
        bool sup = false;
        if (inter > 0.0f) {
            float uni = ljn + (pv.y - pv.x + 1.0f) - inter;
            sup = (inter / uni) > 0.7f;          // IEEE div, same rounding as reference
        }
        if ((ibase + t < j) && sup) bits |= (1ULL << t);
    }
    maskT[(size_t)b * TWORDS + (size_t)((wj * (wj + 1) / 2) + wi) * 64 + (tid & 63)] = bits;
}

// ---------------- Kernel 4: single-wave reduce, column-prefetch greedy (NO apply step) ----------------
__global__ __launch_bounds__(64, 1) void k_reduce(const unsigned long long* __restrict__ maskT,
                                                  const float2* __restrict__ srt,
                                                  float* __restrict__ out) {
    const int b = blockIdx.x;
    const int lane = threadIdx.x;
    __shared__ unsigned long long colbuf[2][2048];   // 2 x 16 KB double buffer
    __shared__ unsigned long long Kl[32];            // kept bitset per window
    __shared__ int sKl[POST_NMS];

    const unsigned long long* mTb = maskT + (size_t)b * TWORDS;

    // stage window wv's column block ((wv+1) words x 64 lanes) into colbuf[wv&1]
    auto stage = [&](int wv) {
        const int nIns = (wv + 2) >> 1;              // ceil((wv+1)*512B / 1024B)
        const char* src = (const char*)(mTb + (size_t)(wv * (wv + 1) / 2) * 64) + lane * 16;
        char* dst = (char*)(&colbuf[wv & 1][0]);
        for (int k = 0; k < nIns; ++k)
            gload_lds16(src + k * 1024, dst + k * 1024);
    };

    stage(0);                                        // prologue

    int kept = 0;
    bool done = false;

    for (int w = 0; w < 32 && !done; ++w) {
        asm volatile("s_waitcnt vmcnt(0)" ::: "memory");
        __builtin_amdgcn_sched_barrier(0);
        if (w < 31) stage(w + 1);                    // prefetch next (other buffer)

        const unsigned long long* cw = &colbuf[w & 1][0];
        unsigned long long SUP = 0ULL;
        for (int wi = 0; wi < w; ++wi)
            SUP |= Kl[wi] & cw[(wi << 6) + lane];    // broadcast K read + per-lane col read
        unsigned long long x = cw[(w << 6) + lane];  // within-window suppressor column

        unsigned long long avail = ~__ballot(SUP != 0ULL);
        unsigned long long keptw = 0ULL;
        while (avail) {
            int j = __ffsll((long long)avail) - 1;   // wave-uniform
            if (lane == 0) sKl[kept] = (w << 6) + j;
            kept++; keptw |= (1ULL << j);
            if (kept >= POST_NMS) { done = true; break; }
            unsigned long long supb = __ballot(((x >> j) & 1ULL) != 0ULL);
            avail &= ~supb;
            avail &= ~(1ULL << j);
        }
        if (lane == 0) Kl[w] = keptw;
    }

    __syncthreads();
    for (int t = lane; t < POST_NMS; t += 64) {
        float x1 = 0.0f, x2 = 0.0f;
        if (t < kept) {
            float2 pv = srt[b * PRE2 + sKl[t]];
            x1 = pv.x; x2 = pv.y;
        }
        float* o = out + (size_t)(b * POST_NMS + t) * 3;
        o[0] = (float)b; o[1] = x1; o[2] = x2;
    }
}

extern "C" void kernel_launch(void* const* d_in, const int* in_sizes, int n_in,
                              void* d_out, int out_size, void* d_ws, size_t ws_size,
                              hipStream_t stream) {
    const float* scores = (const float*)d_in[0];
    const float* deltas = (const float*)d_in[1];
    float* out = (float*)d_out;

    char* ws = (char*)d_ws;
    unsigned long long* packed = (unsigned long long*)ws;                   // 1,310,720 B
    float2* prop = (float2*)(ws + 1310720);                                 // 1,310,720 B
    float2* srt  = (float2*)(ws + 2621440);                                 //    65,536 B
    unsigned long long* maskT = (unsigned long long*)(ws + 2686976);        // 1,081,344 B
    unsigned* ghist = (unsigned*)(ws + 3768320);                            // 1,048,576 B

    // Aliases (no new workspace):
    //  - cand lives in ghist's region: ghist is dead after k_thresh, re-zeroed next iter.
    //  - kmin/gcnt live in maskT's head: dead by the time k_mask rewrites every maskT
    //    word that k_reduce later reads.
    unsigned long long* cand = (unsigned long long*)(ws + 3768320);
    unsigned* kminArr = (unsigned*)(ws + 2686976);
    int* gcnt = (int*)(ws + 2686976 + 64);

    hipMemsetAsync(ghist, 0, (size_t)NB * NHB * sizeof(unsigned), stream);
    k_prep<<<(NB * NSEL + 255) / 256, 256, 0, stream>>>(scores, deltas, packed, prop, ghist);
    k_thresh<<<NB, 1024, 0, stream>>>(ghist, kminArr, gcnt);
    k_compact<<<dim3(NSEL / 1024, NB), 1024, 0, stream>>>(packed, kminArr, gcnt, cand);
    k_rank<<<dim3(CAND / 256, NB), 256, 0, stream>>>(cand, gcnt, prop, srt);
    k_mask<<<dim3(8, 32, NB), 256, 0, stream>>>(srt, maskT);
    k_reduce<<<NB, 64, 0, stream>>>(maskT, srt, out);
}

// Round 3
// 95.556 us; speedup vs baseline: 1.3825x; 1.0644x over previous
//
#include <hip/hip_runtime.h>
#include <stdint.h>

#pragma clang fp contract(off)

#define NA 10
#define LL 4096
#define NB 4
#define NSEL (LL * NA)        // 40960 proposals per image
#define PRE2 2048             // NMS candidate window (prefix-stable: 300 kept << 2048)
#define POST_NMS 300
#define CAND 4096             // candidate buffer (threshold overshoot bound)
#define NHB 65536             // 16-bit-prefix histogram buckets
#define TWORDS 33792          // col-major mask words per image: 64 * sum_{w=0..31}(w+1)

__constant__ float c_WS[NA] = {16.f, 32.f, 40.f, 48.f, 64.f, 72.f, 80.f, 96.f, 112.f, 128.f};

// async global->LDS DMA: per-lane 16B from g (per-lane addr), lands at uniform dst + lane*16
__device__ inline void gload_lds16(const void* g, void* l) {
    __builtin_amdgcn_global_load_lds(
        (const __attribute__((address_space(1))) unsigned*)g,
        (__attribute__((address_space(3))) unsigned*)l, 16, 0, 0);
}

// ---------------- Kernel 1: decode (2 elems/thread) + keys + hist + coarse hist ----------------
// 16B vector loads/stores; per-block LDS coarse hist (key>>26) flushed with <=64 atomics
// so k_thresh no longer reads all 64K buckets for its phase A.
__global__ __launch_bounds__(256) void k_prep(const float* __restrict__ scores,
                                              const float* __restrict__ deltas,
                                              unsigned long long* __restrict__ packed,
                                              float2* __restrict__ prop,
                                              unsigned* __restrict__ ghist,
                                              unsigned* __restrict__ gcoarse) {
    __shared__ unsigned shist[64];
    const int tid = threadIdx.x;
    if (tid < 64) shist[tid] = 0;
    __syncthreads();

    const int g = blockIdx.x * 256 + tid;
    const int e = g << 1;               // element pair base; 80 blocks per image exactly
    const int b = e / NSEL;
    const int r = e - b * NSEL;         // r = a*4096 + l, l even
    const int a = r >> 12;
    const int l = r & 4095;

    const float w = c_WS[a];
    const float2 sc2 = *(const float2*)&scores[((b * 20 + 10 + a) << 12) + l];
    const float2 d02 = *(const float2*)&deltas[((b * 20 + 2 * a) << 12) + l];
    const float2 d12 = *(const float2*)&deltas[((b * 20 + 2 * a + 1) << 12) + l];

    unsigned key0, key1;
    float4 pr;
    {
        float ctr = (float)(8 * l + 4);
        float pc = d02.x * w + ctr;                // contract(off): mul then add, matches numpy
        float pl = expf(d12.x) * w;
        float x1 = fminf(fmaxf(pc - 0.5f * pl, 0.0f), 32767.0f);
        float x2 = fminf(fmaxf(pc + 0.5f * pl, 0.0f), 32767.0f);
        float sc = sc2.x;
        if (x2 - x1 + 1.0f < 8.0f) sc = 0.0f;
        unsigned u = __float_as_uint(sc);
        key0 = (u & 0x80000000u) ? ~u : (u | 0x80000000u);
        pr.x = x1; pr.y = x2;
    }
    {
        float ctr = (float)(8 * (l + 1) + 4);
        float pc = d02.y * w + ctr;
        float pl = expf(d12.y) * w;
        float x1 = fminf(fmaxf(pc - 0.5f * pl, 0.0f), 32767.0f);
        float x2 = fminf(fmaxf(pc + 0.5f * pl, 0.0f), 32767.0f);
        float sc = sc2.y;
        if (x2 - x1 + 1.0f < 8.0f) sc = 0.0f;
        unsigned u = __float_as_uint(sc);
        key1 = (u & 0x80000000u) ? ~u : (u | 0x80000000u);
        pr.z = x1; pr.w = x2;
    }

    // reference's flat index i = l*NA + a, inverted for descending tie-break
    const unsigned long long p0 =
        ((unsigned long long)key0 << 32) | (unsigned)(0xFFFFFFFFu - (unsigned)(l * NA + a));
    const unsigned long long p1 =
        ((unsigned long long)key1 << 32) | (unsigned)(0xFFFFFFFFu - (unsigned)((l + 1) * NA + a));

    *(ulonglong2*)&packed[b * NSEL + r] = make_ulonglong2(p0, p1);   // 16B, r even
    *(float4*)&prop[b * NSEL + r] = pr;                              // 16B, r even

    atomicAdd(&ghist[b * NHB + (key0 >> 16)], 1u);
    atomicAdd(&ghist[b * NHB + (key1 >> 16)], 1u);
    const unsigned c0 = key0 >> 26, c1 = key1 >> 26;
    if (c0 == c1) atomicAdd(&shist[c0], 2u);
    else { atomicAdd(&shist[c0], 1u); atomicAdd(&shist[c1], 1u); }

    __syncthreads();
    if (tid < 64) {
        unsigned v = shist[tid];
        if (v) atomicAdd(&gcoarse[(b << 6) + tid], v);   // b uniform per block
    }
}

// ---------------- Kernel 2a: threshold find (coarse hist precomputed by k_prep) ----------------
__global__ __launch_bounds__(1024) void k_thresh(const unsigned* __restrict__ ghist,
                                                 const unsigned* __restrict__ gcoarse,
                                                 unsigned* __restrict__ kminArr,
                                                 int* __restrict__ gcnt) {
    __shared__ unsigned coarse[64];
    __shared__ unsigned wsum[16];
    __shared__ unsigned sAfter;
    __shared__ int sC;

    const int tid = threadIdx.x;
    const int lane = tid & 63;
    const int wv = tid >> 6;
    const int b = blockIdx.x;
    const unsigned* gh = ghist + b * NHB;

    if (tid == 0) gcnt[b] = 0;
    if (tid < 64) coarse[tid] = gcoarse[(b << 6) + tid];
    __syncthreads();

    // --- Phase B: wave 0 suffix-scans 64 chunk sums, finds crossing chunk ---
    if (wv == 0) {
        unsigned v = coarse[lane];
        unsigned inc = v;
        #pragma unroll
        for (int d = 1; d < 64; d <<= 1) {
            unsigned u = (unsigned)__shfl_down((int)inc, d, 64);
            if (lane + d < 64) inc += u;
        }
        if (inc >= (unsigned)PRE2 && (inc - v) < (unsigned)PRE2) { sC = lane; sAfter = inc - v; }
    }
    __syncthreads();

    // --- Phase C: scan crossing chunk's 1024 buckets (coalesced, shfl-hierarchical) ---
    {
        const int C = sC;
        const unsigned after = sAfter;
        unsigned v = gh[(C << 10) + tid];
        unsigned inc = v;
        #pragma unroll
        for (int d = 1; d < 64; d <<= 1) {
            unsigned u = (unsigned)__shfl_down((int)inc, d, 64);
            if (lane + d < 64) inc += u;
        }
        if (lane == 0) wsum[wv] = inc;
        __syncthreads();
        if (tid < 16) {
            unsigned t = wsum[tid];
            unsigned winc = t;
            #pragma unroll
            for (int d = 1; d < 16; d <<= 1) {
                unsigned u = (unsigned)__shfl_down((int)winc, d, 64);
                if (tid + d < 16) winc += u;
            }
            wsum[tid] = winc - t;            // sum of waves strictly after tid
        }
        __syncthreads();
        unsigned glob = inc + wsum[wv] + after;      // suffix including own bucket
        if (glob >= (unsigned)PRE2 && (glob - v) < (unsigned)PRE2)
            kminArr[b] = ((unsigned)((C << 10) + tid)) << 16;
    }
}

// ---------------- Kernel 2b: wide unordered compaction (block-aggregated atomics) ----------------
__global__ __launch_bounds__(1024) void k_compact(const unsigned long long* __restrict__ packed,
                                                  const unsigned* __restrict__ kminArr,
                                                  int* __restrict__ gcnt,
                                                  unsigned long long* __restrict__ cand) {
    __shared__ int woff[16];
    __shared__ int sbase;
    const int b = blockIdx.y;
    const int tid = threadIdx.x;
    const int lane = tid & 63;
    const int wv = tid >> 6;

    const unsigned km = kminArr[b];
    const unsigned long long p = packed[b * NSEL + (blockIdx.x << 10) + tid];
    const bool pred = ((unsigned)(p >> 32) >= km);
    const unsigned long long m = __ballot(pred);
    if (lane == 0) woff[wv] = (int)__popcll(m);
    __syncthreads();
    if (tid < 16) {
        int v = woff[tid];
        int inc = v;
        #pragma unroll
        for (int d = 1; d < 16; d <<= 1) {
            int u = __shfl_up(inc, d, 64);
            if (tid >= d) inc += u;
        }
        woff[tid] = inc - v;                 // exclusive prefix over waves
        if (tid == 15) sbase = atomicAdd(&gcnt[b], inc);   // one global atomic per block
    }
    __syncthreads();
    if (pred) {
        int pos = sbase + woff[wv] + (int)__popcll(m & ((1ULL << lane) - 1ULL));
        if (pos < CAND) cand[b * CAND + pos] = p;
    }
}

// ---------------- Kernel 2c: rank-scatter, LDS-staged ----------------
// rank_i = #{j : key_j > key_i}: exact descending-sort position (keys unique).
__global__ __launch_bounds__(256) void k_rank(const unsigned long long* __restrict__ cand,
                                              const int* __restrict__ gcnt,
                                              const float2* __restrict__ prop,
                                              float2* __restrict__ srt) {
    __shared__ __align__(16) unsigned long long keys[CAND];   // 32 KB
    __shared__ unsigned part[4][64][4];                        // 4 KB partial ranks

    const int b = blockIdx.y;
    const int n0 = gcnt[b];
    const int n = n0 < CAND ? n0 : CAND;
    const int ib = blockIdx.x * 256;
    if (ib >= n) return;                       // uniform per block: safe before syncs

    const int tid = threadIdx.x;
    const int lane = tid & 63;
    const int wv = tid >> 6;
    const unsigned long long* cb = cand + b * CAND;

    // --- stage: coalesced bulk load, zero-pad to multiple of 8 (0 never outranks a real key) ---
    const int nP = (n + 7) & ~7;
    for (int j = tid; j < nP; j += 256)
        keys[j] = (j < n) ? cb[j] : 0ULL;
    __syncthreads();

    // --- my 4 candidates' keys (i = ib + 4*lane + c); reads past n are pad/garbage, guarded later ---
    const int i0 = ib + (lane << 2);
    unsigned long long k0 = keys[i0 + 0];
    unsigned long long k1 = keys[i0 + 1];
    unsigned long long k2 = keys[i0 + 2];
    unsigned long long k3 = keys[i0 + 3];

    // --- wave wv scans j-slice [wv*q, wv*q+q), q even -> 16B-aligned pair reads ---
    const int q = nP >> 2;
    const ulonglong2* keys2 = (const ulonglong2*)keys;
    const int p0 = (wv * q) >> 1;
    const int pn = q >> 1;
    unsigned r0 = 0, r1 = 0, r2 = 0, r3 = 0;
    #pragma unroll 4
    for (int p = 0; p < pn; ++p) {
        ulonglong2 kj = keys2[p0 + p];         // broadcast (all lanes same addr): conflict-free
        r0 += (kj.x > k0); r0 += (kj.y > k0);
        r1 += (kj.x > k1); r1 += (kj.y > k1);
        r2 += (kj.x > k2); r2 += (kj.y > k2);
        r3 += (kj.x > k3); r3 += (kj.y > k3);
    }
    part[wv][lane][0] = r0; part[wv][lane][1] = r1;
    part[wv][lane][2] = r2; part[wv][lane][3] = r3;
    __syncthreads();

    // --- combine partials, decode, gather box, scatter to rank position ---
    const int ig = ib + tid;
    if (ig < n) {
        const int l_ = tid >> 2, c_ = tid & 3;
        unsigned r = part[0][l_][c_] + part[1][l_][c_] + part[2][l_][c_] + part[3][l_][c_];
        if (r < PRE2) {
            unsigned long long k = keys[ig];
            unsigned idx_ = 0xFFFFFFFFu - (unsigned)k;
            unsigned a_ = idx_ % 10u, l2_ = idx_ / 10u;
            srt[b * PRE2 + r] = prop[b * NSEL + (a_ << 12) + l2_];
        }
    }
}

// ---------------- Kernel 3: COLUMN-major suppression mask over top-2048 ----------------
__global__ __launch_bounds__(256) void k_mask(const float2* __restrict__ srt,
                                              unsigned long long* __restrict__ maskT) {
    const int g  = blockIdx.x;          // wi in [4g, 4g+3]
    const int wj = blockIdx.y;
    const int b  = blockIdx.z;
    if (g * 4 > wj) return;             // whole group above diagonal

    __shared__ float2 lj[256];
    const int tid = threadIdx.x;
    lj[tid] = srt[b * PRE2 + (g << 8) + tid];    // suppressor candidates (4 words)
    __syncthreads();

    const int wi = (g << 2) + (tid >> 6);
    if (wi > wj) return;
    const int j = (wj << 6) + (tid & 63);

    float2 pj = srt[b * PRE2 + j];
    float ljn = pj.y - pj.x + 1.0f;
    unsigned long long bits = 0ULL;
    const int lbase = (tid >> 6) * 64;
    const int ibase = wi << 6;
    #pragma unroll 4
    for (int t = 0; t < 64; ++t) {
        float2 pv = lj[lbase + t];
        float inter = fminf(pj.y, pv.y) - fmaxf(pj.x, pv.x) + 1.0f;
        bool sup = false;
        if (inter > 0.0f) {
            float uni = ljn + (pv.y - pv.x + 1.0f) - inter;
            sup = (inter / uni) > 0.7f;          // IEEE div, same rounding as reference
        }
        if ((ibase + t < j) && sup) bits |= (1ULL << t);
    }
    maskT[(size_t)b * TWORDS + (size_t)((wj * (wj + 1) / 2) + wi) * 64 + (tid & 63)] = bits;
}

// ---------------- Kernel 4: single-wave greedy, DEPTH-4 column prefetch pipeline ----------------
// Round-2 theory: 1-deep prefetch + vmcnt(0) drain exposed ~500-900cy cross-XCD latency
// per window (32x). Now every stage is a FIXED 16 x global_load_lds (full 16 KB; window-31
// block ends exactly at TWORDS so over-fetch stays in bounds), 4 LDS buffers, and a counted
// s_waitcnt vmcnt(48): exactly 3 stages (48 ops) remain in flight, giving ~3 windows of
// compute+greedy to hide each stage's latency. Dummy stages past window 31 keep the
// 48-outstanding invariant with no tail cases.
__global__ __launch_bounds__(64, 1) void k_reduce(const unsigned long long* __restrict__ maskT,
                                                  const float2* __restrict__ srt,
                                                  float* __restrict__ out) {
    const int b = blockIdx.x;
    const int lane = threadIdx.x;
    __shared__ unsigned long long colbuf[4][2048];   // 4 x 16 KB
    __shared__ unsigned long long Kl[32];            // kept bitset per window
    __shared__ int sKl[POST_NMS];

    const unsigned long long* mTb = maskT + (size_t)b * TWORDS;

    auto stage = [&](int wv, int buf) {              // fixed 16 KB stage (16 VMEM ops)
        const char* src = (const char*)(mTb + (size_t)(wv * (wv + 1) / 2) * 64) + lane * 16;
        char* dst = (char*)(&colbuf[buf][0]);
        #pragma unroll
        for (int k = 0; k < 16; ++k)
            gload_lds16(src + k * 1024, dst + k * 1024);
    };

    stage(0, 0); stage(1, 1); stage(2, 2); stage(3, 3);   // prologue: 64 ops in flight

    int kept = 0;
    bool done = false;

    for (int w = 0; w < 32 && !done; ++w) {
        // stages w+1..w+3 (48 ops) may stay outstanding; stage w must be complete
        asm volatile("s_waitcnt vmcnt(48)" ::: "memory");
        __builtin_amdgcn_sched_barrier(0);

        const unsigned long long* cw = &colbuf[w & 3][0];
        unsigned long long SUP = 0ULL;
        for (int wi = 0; wi < w; ++wi)
            SUP |= Kl[wi] & cw[(wi << 6) + lane];    // broadcast K read + per-lane col read
        unsigned long long x = cw[(w << 6) + lane];  // within-window suppressor column

        unsigned long long avail = ~__ballot(SUP != 0ULL);
        // retire all LDS reads of this buffer, pin x, THEN reuse the buffer slot for w+4
        asm volatile("s_waitcnt lgkmcnt(0)" ::: "memory");
        __builtin_amdgcn_sched_barrier(0);
        asm volatile("" : "+v"(x));
        {
            int nx = w + 4;
            stage(nx < 31 ? nx : 31, nx & 3);        // nx>=32: dummy re-stage keeps vmcnt invariant
        }

        unsigned long long keptw = 0ULL;
        while (avail) {
            int j = __ffsll((long long)avail) - 1;   // wave-uniform
            if (lane == 0) sKl[kept] = (w << 6) + j;
            kept++; keptw |= (1ULL << j);
            if (kept >= POST_NMS) { done = true; break; }
            unsigned long long supb = __ballot(((x >> j) & 1ULL) != 0ULL);
            avail &= ~supb;
            avail &= ~(1ULL << j);
        }
        if (lane == 0) Kl[w] = keptw;
    }

    __syncthreads();
    for (int t = lane; t < POST_NMS; t += 64) {
        float x1 = 0.0f, x2 = 0.0f;
        if (t < kept) {
            float2 pv = srt[b * PRE2 + sKl[t]];
            x1 = pv.x; x2 = pv.y;
        }
        float* o = out + (size_t)(b * POST_NMS + t) * 3;
        o[0] = (float)b; o[1] = x1; o[2] = x2;
    }
}

extern "C" void kernel_launch(void* const* d_in, const int* in_sizes, int n_in,
                              void* d_out, int out_size, void* d_ws, size_t ws_size,
                              hipStream_t stream) {
    const float* scores = (const float*)d_in[0];
    const float* deltas = (const float*)d_in[1];
    float* out = (float*)d_out;

    char* ws = (char*)d_ws;
    unsigned long long* packed = (unsigned long long*)ws;                   // 1,310,720 B
    float2* prop = (float2*)(ws + 1310720);                                 // 1,310,720 B
    float2* srt  = (float2*)(ws + 2621440);                                 //    65,536 B
    unsigned long long* maskT = (unsigned long long*)(ws + 2686976);        // 1,081,344 B
    unsigned* ghist = (unsigned*)(ws + 3768320);                            // 1,048,576 B
    unsigned* gcoarse = (unsigned*)(ws + 4816896);                          //     1,024 B

    // Aliases (no new workspace):
    //  - cand lives in ghist's region: ghist is dead after k_thresh, re-zeroed next iter.
    //  - kmin/gcnt live in maskT's head: dead by the time k_mask rewrites every maskT
    //    word that k_reduce later reads.
    unsigned long long* cand = (unsigned long long*)(ws + 3768320);
    unsigned* kminArr = (unsigned*)(ws + 2686976);
    int* gcnt = (int*)(ws + 2686976 + 64);

    hipMemsetAsync(ghist, 0, (size_t)NB * NHB * sizeof(unsigned) + NB * 64 * sizeof(unsigned), stream);
    k_prep<<<NB * NSEL / 512, 256, 0, stream>>>(scores, deltas, packed, prop, ghist, gcoarse);
    k_thresh<<<NB, 1024, 0, stream>>>(ghist, gcoarse, kminArr, gcnt);
    k_compact<<<dim3(NSEL / 1024, NB), 1024, 0, stream>>>(packed, kminArr, gcnt, cand);
    k_rank<<<dim3(CAND / 256, NB), 256, 0, stream>>>(cand, gcnt, prop, srt);
    k_mask<<<dim3(8, 32, NB), 256, 0, stream>>>(srt, maskT);
    k_reduce<<<NB, 64, 0, stream>>>(maskT, srt, out);
}